// Round 2
// baseline (262.474 us; speedup 1.0000x reference)
//
#include <hip/hip_runtime.h>
#include <stdint.h>

// Problem: B=65536, F=512, H=256, A=4, P=2, E=32. All float tensors fp32.
// Algebraic collapse (no activation between the Linears):
//   mlp2(x) = x @ (W1@W2) + (b1@W2 + b2)
// All six heads fuse into one [B,512] @ [512,15] GEMM; the pointgoal-concat
// heads add a rank-2 correction pg @ (Wp@Meff_tail) and a folded bias.
// Per-row select by task_id in the epilogue. Compute path: features rounded
// to bf16 (RTNE) in-register, bf16 MFMA, fp32 accumulate (tolerance is
// bf16-floor: 8*2^-8*max).

typedef __attribute__((ext_vector_type(8))) short bf16x8;
typedef __attribute__((ext_vector_type(4))) float f32x4;

__device__ __forceinline__ unsigned short f2bf(float f) {
    union { unsigned int i; float f; } v; v.f = f;
    unsigned int u = v.i;
    return (unsigned short)((u + 0x7fffu + ((u >> 16) & 1u)) >> 16);
}
// pack two fp32 -> (lo=a, hi=b) bf16 pair, RTNE
__device__ __forceinline__ unsigned int pkbf(float a, float b) {
    union { unsigned int i; float f; } va, vb; va.f = a; vb.f = b;
    unsigned int ua = (va.i + 0x7fffu + ((va.i >> 16) & 1u)) >> 16;
    unsigned int ub = (vb.i + 0x7fffu + ((vb.i >> 16) & 1u)) & 0xffff0000u;
    return (ua & 0xffffu) | ub;
}

struct HeadPtrs {
    const float* W1[6];
    const float* b1[6];
    const float* W2[6];
    const float* b2[6];
};

// ---------------------------------------------------------------------------
// P1: Meff[c][k] = sum_j W1[k][j] * W2[j][a]  (fp32), plus bias row at k==Kh:
//     sum_j b1[j]*W2[j][a] + b2[a].
// cols c: 0=c0(value), 1-4=a0, 5=c1, 6-9=a1, 10=c2, 11-14=a2.
// Mfull layout: [15][548] fp32 (Kh=512 or 544; bias row at index Kh).
// ---------------------------------------------------------------------------
__global__ void precompute_main(HeadPtrs hp, float* __restrict__ Mfull) {
    int c = blockIdx.x;                 // 0..14
    int tid = threadIdx.x;              // 0..255
    int k = blockIdx.y * 256 + tid;     // 0..767
    int hd, a;
    if (c == 0)       { hd = 3; a = 0; }
    else if (c < 5)   { hd = 0; a = c - 1; }
    else if (c == 5)  { hd = 4; a = 0; }
    else if (c < 10)  { hd = 1; a = c - 6; }
    else if (c == 10) { hd = 5; a = 0; }
    else              { hd = 2; a = c - 11; }
    int Kh = (hd == 2 || hd == 5) ? 544 : 512;   // a2/c2 take [F+E] rows
    int A  = (hd < 3) ? 4 : 1;

    __shared__ float w2s[256];
    w2s[tid] = hp.W2[hd][tid * A + a];
    __syncthreads();
    if (k > Kh) return;

    const float* row = (k < Kh) ? (hp.W1[hd] + (size_t)k * 256) : hp.b1[hd];
    float acc = (k == Kh) ? hp.b2[hd][a] : 0.f;
    const float4* r4 = (const float4*)row;
    #pragma unroll 8
    for (int j0 = 0; j0 < 64; ++j0) {
        float4 w = r4[j0];
        acc += w.x * w2s[j0 * 4]     + w.y * w2s[j0 * 4 + 1]
             + w.z * w2s[j0 * 4 + 2] + w.w * w2s[j0 * 4 + 3];
    }
    Mfull[c * 548 + k] = acc;
}

// ---------------------------------------------------------------------------
// P2: (a) fold the E=32 tail rows through Wp/bp into V[2][16] and bias[16];
//     (b) pack Meff[:, 0:512] into MFMA B-fragment order as bf16:
//         lane l -> n = l&15, k = s*32 + (l>>4)*8 + j; stored so the main
//         kernel reads bfrag[s*64 + l] as one dwordx4.
// ---------------------------------------------------------------------------
__global__ void precompute_pack(const float* __restrict__ Mfull,
                                const float* __restrict__ a2Wp,
                                const float* __restrict__ a2bp,
                                const float* __restrict__ c2Wp,
                                const float* __restrict__ c2bp,
                                uint4* __restrict__ bfrag,
                                float* __restrict__ bias,
                                float* __restrict__ V) {
    int idx = blockIdx.x * 256 + threadIdx.x;   // 0..1023 = 16 steps * 64 lanes
    int s = idx >> 6, l = idx & 63;
    int q = l >> 4, c = l & 15;
    unsigned int w[4];
    #pragma unroll
    for (int jj = 0; jj < 4; ++jj) {
        int k0 = s * 32 + q * 8 + 2 * jj;       // < 512 always
        unsigned short lo = (c < 15) ? f2bf(Mfull[c * 548 + k0])     : (unsigned short)0;
        unsigned short hi = (c < 15) ? f2bf(Mfull[c * 548 + k0 + 1]) : (unsigned short)0;
        w[jj] = (unsigned int)lo | ((unsigned int)hi << 16);
    }
    bfrag[idx] = make_uint4(w[0], w[1], w[2], w[3]);

    if (blockIdx.x == 0 && threadIdx.x < 16) {
        int cc = threadIdx.x;
        float b = 0.f, v0 = 0.f, v1 = 0.f;
        if (cc < 15) {
            int Kh = (cc >= 10) ? 544 : 512;
            b = Mfull[cc * 548 + Kh];           // b1@W2 + b2
            if (cc >= 10) {
                const float* Wp = (cc == 10) ? c2Wp : a2Wp;   // [2][32]
                const float* bp = (cc == 10) ? c2bp : a2bp;   // [32]
                #pragma unroll 8
                for (int e = 0; e < 32; ++e) {
                    float t = Mfull[cc * 548 + 512 + e];      // Meff tail row
                    b  += bp[e] * t;
                    v0 += Wp[e] * t;          // Wp[0][e]
                    v1 += Wp[32 + e] * t;     // Wp[1][e]
                }
            }
        }
        bias[cc] = b; V[cc] = v0; V[16 + cc] = v1;
    }
}

// ---------------------------------------------------------------------------
// Main: wave handles one 16-row tile. A gathered global->VGPR (fp32), packed
// to bf16 RTNE in-register; B-frags staged in LDS once per block.
// 16x mfma_f32_16x16x32_bf16; epilogue: +bias +pg@V, select by task_id,
// fp32 store. C layout (verified): col = l&15, row = (l>>4)*4 + reg.
// ---------------------------------------------------------------------------
__global__ __launch_bounds__(256) void main_gemm(
    const float* __restrict__ feat,
    const float* __restrict__ pg,
    const int* __restrict__ task,
    const uint4* __restrict__ bfrag,
    const float* __restrict__ bias,
    const float* __restrict__ V,
    float* __restrict__ out)
{
    __shared__ uint4 lds_b[1024];
    int tid = threadIdx.x;
    #pragma unroll
    for (int i = 0; i < 4; ++i) lds_b[tid + 256 * i] = bfrag[tid + 256 * i];
    __syncthreads();

    int l = tid & 63;
    int tile = blockIdx.x * 4 + (tid >> 6);
    int row0 = tile * 16;
    int m = l & 15, q = l >> 4;

    const float4* f4 = (const float4*)feat;
    // one feature row = 512 fp32 = 128 float4; lane needs 8 consecutive
    // floats at elem offset (row0+m)*512 + s*32 + q*8 -> float4 idx +s*8.
    size_t abase = (size_t)(row0 + m) * 128 + q * 2;

    f32x4 acc = {0.f, 0.f, 0.f, 0.f};
    #pragma unroll
    for (int s = 0; s < 16; ++s) {
        float4 x0 = f4[abase + s * 8];
        float4 x1 = f4[abase + s * 8 + 1];
        uint4 av;
        av.x = pkbf(x0.x, x0.y);
        av.y = pkbf(x0.z, x0.w);
        av.z = pkbf(x1.x, x1.y);
        av.w = pkbf(x1.z, x1.w);
        uint4 bv = lds_b[s * 64 + l];
        acc = __builtin_amdgcn_mfma_f32_16x16x32_bf16(
            __builtin_bit_cast(bf16x8, av), __builtin_bit_cast(bf16x8, bv),
            acc, 0, 0, 0);
    }

    int c = m;                        // output column 0..15 (15 = pad)
    int tc = c / 5;                   // task owning this column (3 for pad)
    int jc = c - 5 * tc;              // 0=value, 1..4=logits
    float bc = bias[c], v0 = V[c], v1 = V[16 + c];
    const float2* pg2 = (const float2*)pg;
    #pragma unroll
    for (int i = 0; i < 4; ++i) {
        int r = row0 + q * 4 + i;
        float2 p = pg2[r];
        float val = acc[i] + bc + p.x * v0 + p.y * v1;
        if (c < 15 && task[r] == tc) out[(size_t)r * 5 + jc] = val;
    }
}

extern "C" void kernel_launch(void* const* d_in, const int* in_sizes, int n_in,
                              void* d_out, int out_size, void* d_ws, size_t ws_size,
                              hipStream_t stream)
{
    const float* feat = (const float*)d_in[0];
    const float* pg   = (const float*)d_in[1];
    // head order: a0, a1, a2, c0, c1, c2 (W1 input indices)
    const int w1_idx[6] = {2, 6, 12, 16, 20, 26};
    HeadPtrs hp;
    for (int h = 0; h < 6; ++h) {
        hp.W1[h] = (const float*)d_in[w1_idx[h]];
        hp.b1[h] = (const float*)d_in[w1_idx[h] + 1];
        hp.W2[h] = (const float*)d_in[w1_idx[h] + 2];
        hp.b2[h] = (const float*)d_in[w1_idx[h] + 3];
    }
    const float* a2Wp = (const float*)d_in[10];
    const float* a2bp = (const float*)d_in[11];
    const float* c2Wp = (const float*)d_in[24];
    const float* c2bp = (const float*)d_in[25];
    const int* task = (const int*)d_in[30];
    float* out = (float*)d_out;
    int B = in_sizes[0] / 512;        // 65536

    // ws layout: Mfull fp32 [15][548] | bfrag 16 KB | bias f32[16] | V f32[32]
    char* ws = (char*)d_ws;
    float* Mfull = (float*)ws;                              // 32880 B
    uint4* bfrag = (uint4*)(ws + 32896);                    // 16384 B (16B aligned)
    float* bias  = (float*)(ws + 32896 + 16384);            // 64 B
    float* V     = (float*)(ws + 32896 + 16384 + 64);       // 128 B

    precompute_main<<<dim3(15, 3), 256, 0, stream>>>(hp, Mfull);
    precompute_pack<<<dim3(4), 256, 0, stream>>>(Mfull, a2Wp, a2bp, c2Wp, c2bp,
                                                 bfrag, bias, V);
    int tiles = B / 16;               // 4096 wave-tiles
    main_gemm<<<dim3(tiles / 4), 256, 0, stream>>>(feat, pg, task, bfrag, bias, V, out);
}

// Round 3
// 258.049 us; speedup vs baseline: 1.0171x; 1.0171x over previous
//
#include <hip/hip_runtime.h>
#include <stdint.h>

// Problem: B=65536, F=512, H=256, A=4, P=2, E=32. All float tensors fp32.
// Algebraic collapse (no activation between the Linears):
//   mlp2(x) = x @ (W1@W2) + (b1@W2 + b2)
// All six heads fuse into one [B,512] @ [512,15] GEMM; the pointgoal-concat
// heads add a rank-2 correction pg @ (Wp @ Meff_tail) and a folded bias.
// Per-row select by task_id in the epilogue. Compute path: features rounded
// to bf16 (RTNE) in-register, bf16 MFMA, fp32 accumulate/store (tolerance is
// bf16-floor: 8*2^-8*max|ref|).

typedef __attribute__((ext_vector_type(8))) short bf16x8;
typedef __attribute__((ext_vector_type(4))) float f32x4;

__device__ __forceinline__ unsigned short f2bf(float f) {
    union { unsigned int i; float f; } v; v.f = f;
    unsigned int u = v.i;
    return (unsigned short)((u + 0x7fffu + ((u >> 16) & 1u)) >> 16);
}
// pack two fp32 -> (lo=a, hi=b) bf16 pair, RTNE
__device__ __forceinline__ unsigned int pkbf(float a, float b) {
    union { unsigned int i; float f; } va, vb; va.f = a; vb.f = b;
    unsigned int ua = (va.i + 0x7fffu + ((va.i >> 16) & 1u)) >> 16;
    unsigned int ub = (vb.i + 0x7fffu + ((vb.i >> 16) & 1u)) & 0xffff0000u;
    return (ua & 0xffffu) | ub;
}

struct HeadPtrs {
    const float* W1[6];
    const float* b1[6];
    const float* W2[6];
    const float* b2[6];
};

// ---------------------------------------------------------------------------
// Fused precompute: grid (15 cols, 3 k-chunks) x 256 threads.
//   Meff[c][k] = sum_j W1[k][j] * W2[j][a]  (fp32); bias row at k==Kh is
//   sum_j b1[j]*W2[j][a] + b2[a].
// cols c: 0=c0(value), 1-4=a0, 5=c1, 6-9=a1, 10=c2, 11-14=a2.
// y<2 blocks (k<512): write Meff directly into bfrag as bf16, MFMA B-frag
//   order: ushort index (s*64 + q*16 + c)*8 + j, where s=k>>5, q=(k>>3)&3,
//   j=k&7 (lane l=q*16+n holds B[k = s*32 + q*8 + j][n]).
// y==2 block (k>=512): compute tail rows + bias row, fold through Wp/bp into
//   bias[16] and V[2][16] locally via LDS.
// ---------------------------------------------------------------------------
__global__ void precompute(HeadPtrs hp,
                           const float* __restrict__ a2Wp,
                           const float* __restrict__ a2bp,
                           const float* __restrict__ c2Wp,
                           const float* __restrict__ c2bp,
                           unsigned short* __restrict__ bfrag_u,
                           float* __restrict__ bias,
                           float* __restrict__ V) {
    int c = blockIdx.x;                 // 0..14
    int y = blockIdx.y;                 // 0..2
    int tid = threadIdx.x;              // 0..255
    int k = y * 256 + tid;              // 0..767
    int hd, a;
    if (c == 0)       { hd = 3; a = 0; }
    else if (c < 5)   { hd = 0; a = c - 1; }
    else if (c == 5)  { hd = 4; a = 0; }
    else if (c < 10)  { hd = 1; a = c - 6; }
    else if (c == 10) { hd = 5; a = 0; }
    else              { hd = 2; a = c - 11; }
    int Kh = (hd == 2 || hd == 5) ? 544 : 512;   // a2/c2 take [F+E] rows
    int A  = (hd < 3) ? 4 : 1;

    __shared__ float w2s[256];
    __shared__ float tail[40];
    w2s[tid] = hp.W2[hd][tid * A + a];
    __syncthreads();

    float acc = 0.f;
    if (k <= Kh) {
        const float* row = (k < Kh) ? (hp.W1[hd] + (size_t)k * 256) : hp.b1[hd];
        acc = (k == Kh) ? hp.b2[hd][a] : 0.f;
        const float4* r4 = (const float4*)row;
        #pragma unroll 8
        for (int j0 = 0; j0 < 64; ++j0) {
            float4 w = r4[j0];
            acc += w.x * w2s[j0 * 4]     + w.y * w2s[j0 * 4 + 1]
                 + w.z * w2s[j0 * 4 + 2] + w.w * w2s[j0 * 4 + 3];
        }
    }

    if (y < 2) {
        // k < 512 always: write bf16 B-fragment element
        int s = k >> 5, q = (k >> 3) & 3, j = k & 7;
        bfrag_u[((s * 64 + q * 16 + c) * 8) + j] = f2bf(acc);
        if (c == 0)  // zero the n==15 pad column
            bfrag_u[((s * 64 + q * 16 + 15) * 8) + j] = 0;
    } else {
        if (k <= Kh) tail[k - 512] = acc;     // tail rows + bias row
        __syncthreads();
        if (tid == 0) {
            float b, v0 = 0.f, v1 = 0.f;
            if (Kh == 512) {
                b = tail[0];                  // bias row only
            } else {
                b = tail[32];                 // bias row at k=544
                const float* Wp = (c == 10) ? c2Wp : a2Wp;   // [2][32]
                const float* bp = (c == 10) ? c2bp : a2bp;   // [32]
                #pragma unroll 8
                for (int e = 0; e < 32; ++e) {
                    float t = tail[e];        // Meff tail row e
                    b  += bp[e] * t;
                    v0 += Wp[e] * t;          // Wp[0][e]
                    v1 += Wp[32 + e] * t;     // Wp[1][e]
                }
            }
            bias[c] = b; V[c] = v0; V[16 + c] = v1;
        }
        if (c == 0 && tid == 1) { bias[15] = 0.f; V[15] = 0.f; V[31] = 0.f; }
    }
}

// ---------------------------------------------------------------------------
// Main: wave handles one 16-row tile. A gathered global->VGPR (fp32) with
// explicit deep load batching (16 dwordx4 in flight per wave), packed to bf16
// RTNE in-register; B-frags staged in LDS once per block.
// 16x mfma_f32_16x16x32_bf16; epilogue: +bias +pg@V, select by task_id,
// fp32 store. C layout (verified): col = l&15, row = (l>>4)*4 + reg.
// __launch_bounds__(256,4): cap VGPR at 128 -> 16 waves/CU.
// ---------------------------------------------------------------------------
__global__ __launch_bounds__(256, 4) void main_gemm(
    const float* __restrict__ feat,
    const float* __restrict__ pg,
    const int* __restrict__ task,
    const uint4* __restrict__ bfrag,
    const float* __restrict__ bias,
    const float* __restrict__ V,
    float* __restrict__ out)
{
    __shared__ uint4 lds_b[1024];
    int tid = threadIdx.x;
    #pragma unroll
    for (int i = 0; i < 4; ++i) lds_b[tid + 256 * i] = bfrag[tid + 256 * i];
    __syncthreads();

    int l = tid & 63;
    int tile = blockIdx.x * 4 + (tid >> 6);
    int row0 = tile * 16;
    int m = l & 15, q = l >> 4;

    const float4* f4 = (const float4*)feat;
    // one feature row = 512 fp32 = 128 float4; lane reads 8 consecutive
    // floats at elem offset (row0+m)*512 + s*32 + q*8 -> float4 idx abase+s*8.
    size_t abase = (size_t)(row0 + m) * 128 + q * 2;

    float4 L[8], M[8];
    uint4 av[8];
    f32x4 acc = {0.f, 0.f, 0.f, 0.f};

    // half 0: issue 16 loads
    #pragma unroll
    for (int s = 0; s < 8; ++s) { L[s] = f4[abase + s * 8]; M[s] = f4[abase + s * 8 + 1]; }
    // pack half 0 (waits arrival in issue order)
    #pragma unroll
    for (int s = 0; s < 8; ++s) {
        av[s].x = pkbf(L[s].x, L[s].y); av[s].y = pkbf(L[s].z, L[s].w);
        av[s].z = pkbf(M[s].x, M[s].y); av[s].w = pkbf(M[s].z, M[s].w);
    }
    // half 1: issue 16 loads (reuse L/M), overlapping with half-0 MFMAs
    #pragma unroll
    for (int s = 0; s < 8; ++s) { L[s] = f4[abase + (s + 8) * 8]; M[s] = f4[abase + (s + 8) * 8 + 1]; }
    // MFMA half 0
    #pragma unroll
    for (int s = 0; s < 8; ++s) {
        uint4 bv = lds_b[s * 64 + l];
        acc = __builtin_amdgcn_mfma_f32_16x16x32_bf16(
            __builtin_bit_cast(bf16x8, av[s]), __builtin_bit_cast(bf16x8, bv),
            acc, 0, 0, 0);
    }
    // pack half 1
    #pragma unroll
    for (int s = 0; s < 8; ++s) {
        av[s].x = pkbf(L[s].x, L[s].y); av[s].y = pkbf(L[s].z, L[s].w);
        av[s].z = pkbf(M[s].x, M[s].y); av[s].w = pkbf(M[s].z, M[s].w);
    }
    // MFMA half 1
    #pragma unroll
    for (int s = 0; s < 8; ++s) {
        uint4 bv = lds_b[(s + 8) * 64 + l];
        acc = __builtin_amdgcn_mfma_f32_16x16x32_bf16(
            __builtin_bit_cast(bf16x8, av[s]), __builtin_bit_cast(bf16x8, bv),
            acc, 0, 0, 0);
    }

    int c = m;                        // output column 0..15 (15 = pad)
    int tc = c / 5;                   // task owning this column (3 for pad)
    int jc = c - 5 * tc;              // 0=value, 1..4=logits
    float bc = bias[c], v0 = V[c], v1 = V[16 + c];
    const float2* pg2 = (const float2*)pg;
    #pragma unroll
    for (int i = 0; i < 4; ++i) {
        int r = row0 + q * 4 + i;
        float2 p = pg2[r];
        float val = acc[i] + bc + p.x * v0 + p.y * v1;
        if (c < 15 && task[r] == tc) out[(size_t)r * 5 + jc] = val;
    }
}

extern "C" void kernel_launch(void* const* d_in, const int* in_sizes, int n_in,
                              void* d_out, int out_size, void* d_ws, size_t ws_size,
                              hipStream_t stream)
{
    const float* feat = (const float*)d_in[0];
    const float* pg   = (const float*)d_in[1];
    // head order: a0, a1, a2, c0, c1, c2 (W1 input indices)
    const int w1_idx[6] = {2, 6, 12, 16, 20, 26};
    HeadPtrs hp;
    for (int h = 0; h < 6; ++h) {
        hp.W1[h] = (const float*)d_in[w1_idx[h]];
        hp.b1[h] = (const float*)d_in[w1_idx[h] + 1];
        hp.W2[h] = (const float*)d_in[w1_idx[h] + 2];
        hp.b2[h] = (const float*)d_in[w1_idx[h] + 3];
    }
    const float* a2Wp = (const float*)d_in[10];
    const float* a2bp = (const float*)d_in[11];
    const float* c2Wp = (const float*)d_in[24];
    const float* c2bp = (const float*)d_in[25];
    const int* task = (const int*)d_in[30];
    float* out = (float*)d_out;
    int B = in_sizes[0] / 512;        // 65536

    // ws layout: bfrag bf16 16 KB | bias f32[16] | V f32[32]
    char* ws = (char*)d_ws;
    unsigned short* bfrag_u = (unsigned short*)ws;          // 16384 B
    float* bias  = (float*)(ws + 16384);                    // 64 B
    float* V     = (float*)(ws + 16384 + 64);               // 128 B

    precompute<<<dim3(15, 3), 256, 0, stream>>>(hp, a2Wp, a2bp, c2Wp, c2bp,
                                                bfrag_u, bias, V);
    int tiles = B / 16;               // 4096 wave-tiles
    main_gemm<<<dim3(tiles / 4), 256, 0, stream>>>(feat, pg, task,
                                                   (const uint4*)bfrag_u,
                                                   bias, V, out);
}